// Round 1
// baseline (2366.095 us; speedup 1.0000x reference)
//
#include <hip/hip_runtime.h>

#define B_DIM 2048
#define IN_DIM 1024
#define M_DIM 256
#define P_DIM 32896   // 256*257/2

// ---------------- Stage 1: C[B,P] = X @ W^T + bias (fp32 tiled SGEMM) ----------------
// Tile 128x128, BK=16, 256 threads, 8x8 micro-tile (split 4+4 rows/cols for LDS banking)
__global__ __launch_bounds__(256) void gemm1_kernel(
    const float* __restrict__ X, const float* __restrict__ W,
    const float* __restrict__ bias, float* __restrict__ C)
{
    __shared__ float As[16][132];   // [k][m], +4 pad
    __shared__ float Bs[16][132];   // [k][n]

    const int t    = threadIdx.x;
    const int tx   = t & 15;
    const int ty   = t >> 4;
    const int row0 = blockIdx.y * 128;
    const int col0 = blockIdx.x * 128;

    const int lrow = t >> 2;          // 0..63: staging row
    const int lk   = (t & 3) << 2;    // 0,4,8,12: staging k offset

    const float* Xb = X + (size_t)(row0 + lrow) * IN_DIM + lk;
    const float* Wb = W + (size_t)(col0 + lrow) * IN_DIM + lk;

    float acc[8][8];
#pragma unroll
    for (int i = 0; i < 8; ++i)
#pragma unroll
        for (int j = 0; j < 8; ++j) acc[i][j] = 0.f;

    for (int k0 = 0; k0 < IN_DIM; k0 += 16) {
        float4 a0 = *reinterpret_cast<const float4*>(Xb + k0);
        float4 a1 = *reinterpret_cast<const float4*>(Xb + 64 * IN_DIM + k0);
        float4 b0 = *reinterpret_cast<const float4*>(Wb + k0);
        float4 b1 = *reinterpret_cast<const float4*>(Wb + 64 * IN_DIM + k0);
        __syncthreads();   // previous iter's compute done before overwrite
        As[lk + 0][lrow] = a0.x; As[lk + 1][lrow] = a0.y;
        As[lk + 2][lrow] = a0.z; As[lk + 3][lrow] = a0.w;
        As[lk + 0][lrow + 64] = a1.x; As[lk + 1][lrow + 64] = a1.y;
        As[lk + 2][lrow + 64] = a1.z; As[lk + 3][lrow + 64] = a1.w;
        Bs[lk + 0][lrow] = b0.x; Bs[lk + 1][lrow] = b0.y;
        Bs[lk + 2][lrow] = b0.z; Bs[lk + 3][lrow] = b0.w;
        Bs[lk + 0][lrow + 64] = b1.x; Bs[lk + 1][lrow + 64] = b1.y;
        Bs[lk + 2][lrow + 64] = b1.z; Bs[lk + 3][lrow + 64] = b1.w;
        __syncthreads();
#pragma unroll
        for (int k = 0; k < 16; ++k) {
            float a[8], b[8];
            *reinterpret_cast<float4*>(&a[0]) = *reinterpret_cast<const float4*>(&As[k][ty * 4]);
            *reinterpret_cast<float4*>(&a[4]) = *reinterpret_cast<const float4*>(&As[k][64 + ty * 4]);
            *reinterpret_cast<float4*>(&b[0]) = *reinterpret_cast<const float4*>(&Bs[k][tx * 4]);
            *reinterpret_cast<float4*>(&b[4]) = *reinterpret_cast<const float4*>(&Bs[k][64 + tx * 4]);
#pragma unroll
            for (int i = 0; i < 8; ++i)
#pragma unroll
                for (int j = 0; j < 8; ++j)
                    acc[i][j] = fmaf(a[i], b[j], acc[i][j]);
        }
    }

    // Epilogue: rows row0+ty*4+{0..3} and +64; cols col0+tx*4+{0..3} and +64
    const int r0 = row0 + ty * 4;
    const int c0 = col0 + tx * 4;
    float4 bv0 = *reinterpret_cast<const float4*>(&bias[c0]);
    float4 bv1 = *reinterpret_cast<const float4*>(&bias[c0 + 64]);
#pragma unroll
    for (int g = 0; g < 2; ++g) {
#pragma unroll
        for (int i = 0; i < 4; ++i) {
            const int r  = r0 + g * 64 + i;
            const int ai = g * 4 + i;
            float4 v0 = make_float4(acc[ai][0] + bv0.x, acc[ai][1] + bv0.y,
                                    acc[ai][2] + bv0.z, acc[ai][3] + bv0.w);
            float4 v1 = make_float4(acc[ai][4] + bv1.x, acc[ai][5] + bv1.y,
                                    acc[ai][6] + bv1.z, acc[ai][7] + bv1.w);
            *reinterpret_cast<float4*>(&C[(size_t)r * P_DIM + c0]) = v0;
            *reinterpret_cast<float4*>(&C[(size_t)r * P_DIM + c0 + 64]) = v1;
        }
    }
}

// ---------------- Stage 2: O[b] = L_b @ L_b^T (batched SYRK, packed tril input) ----------------
// One block = one (batch, tile-pair). 64x64 tiles, 4x4 micro, symmetry + k-skip.
__global__ __launch_bounds__(256) void syrk_kernel(
    const float* __restrict__ Lp, float* __restrict__ Out)
{
    __shared__ float As[16][68];   // [k][i]
    __shared__ float Bs[16][68];   // [k][j]

    const int bid   = blockIdx.x;
    const int batch = bid / 10;
    const int p     = bid - batch * 10;
    int ti, tj;
    if (p == 0)      { ti = 0; tj = 0; }
    else if (p < 3)  { ti = 1; tj = p - 1; }
    else if (p < 6)  { ti = 2; tj = p - 3; }
    else             { ti = 3; tj = p - 6; }

    const int t    = threadIdx.x;
    const int tx   = t & 15;
    const int ty   = t >> 4;
    const int srow = t >> 2;          // 0..63
    const int sk   = (t & 3) << 2;    // 0,4,8,12

    const int i0 = ti * 64, j0 = tj * 64;
    const int ia = i0 + srow;         // global row staged into As
    const int jb = j0 + srow;         // global row staged into Bs
    const float* Lb = Lp + (size_t)batch * P_DIM;
    const size_t abase = ((size_t)ia * (ia + 1)) >> 1;
    const size_t bbase = ((size_t)jb * (jb + 1)) >> 1;

    float acc[4][4];
#pragma unroll
    for (int i = 0; i < 4; ++i)
#pragma unroll
        for (int j = 0; j < 4; ++j) acc[i][j] = 0.f;

    const int nsteps = (tj + 1) * 4;   // k only runs to min(i,j) <= j0+63
    for (int s = 0; s < nsteps; ++s) {
        const int k0 = s * 16;
        float av[4], bv[4];
#pragma unroll
        for (int e = 0; e < 4; ++e) {
            const int k = k0 + sk + e;
            float va = 0.f, vb = 0.f;
            if (k <= ia) {                      // tril: zero above diagonal
                va = Lb[abase + k];
                if (k == ia) va = fmaxf(va, 0.f);   // ReLU on diagonal
            }
            if (k <= jb) {
                vb = Lb[bbase + k];
                if (k == jb) vb = fmaxf(vb, 0.f);
            }
            av[e] = va; bv[e] = vb;
        }
        __syncthreads();
#pragma unroll
        for (int e = 0; e < 4; ++e) {
            As[sk + e][srow] = av[e];
            Bs[sk + e][srow] = bv[e];
        }
        __syncthreads();
#pragma unroll
        for (int k = 0; k < 16; ++k) {
            float a[4], b[4];
            *reinterpret_cast<float4*>(&a[0]) = *reinterpret_cast<const float4*>(&As[k][ty * 4]);
            *reinterpret_cast<float4*>(&b[0]) = *reinterpret_cast<const float4*>(&Bs[k][tx * 4]);
#pragma unroll
            for (int i = 0; i < 4; ++i)
#pragma unroll
                for (int j = 0; j < 4; ++j)
                    acc[i][j] = fmaf(a[i], b[j], acc[i][j]);
        }
    }

    float* Ob = Out + (size_t)batch * (M_DIM * M_DIM);
    const int oi = i0 + ty * 4;
    const int oj = j0 + tx * 4;
#pragma unroll
    for (int i = 0; i < 4; ++i) {
        float4 v = make_float4(acc[i][0], acc[i][1], acc[i][2], acc[i][3]);
        *reinterpret_cast<float4*>(&Ob[(oi + i) * M_DIM + oj]) = v;
    }
    if (ti != tj) {   // mirror write O[j][i] = O[i][j]
#pragma unroll
        for (int i = 0; i < 4; ++i)
#pragma unroll
            for (int j = 0; j < 4; ++j)
                Ob[(oj + j) * M_DIM + oi + i] = acc[i][j];
    }
}

extern "C" void kernel_launch(void* const* d_in, const int* in_sizes, int n_in,
                              void* d_out, int out_size, void* d_ws, size_t ws_size,
                              hipStream_t stream)
{
    (void)in_sizes; (void)n_in; (void)out_size; (void)ws_size;
    const float* x = (const float*)d_in[0];
    const float* W = (const float*)d_in[1];
    const float* b = (const float*)d_in[2];
    float* C = (float*)d_ws;    // needs 2048*32896*4 = 257 MiB scratch
    float* O = (float*)d_out;

    dim3 g1(P_DIM / 128, B_DIM / 128);   // (257, 16)
    gemm1_kernel<<<g1, dim3(256), 0, stream>>>(x, W, b, C);
    syrk_kernel<<<dim3(B_DIM * 10), dim3(256), 0, stream>>>(C, O);
}

// Round 2
// 559.189 us; speedup vs baseline: 4.2313x; 4.2313x over previous
//
#include <hip/hip_runtime.h>

#define B_DIM 2048
#define IN_DIM 1024
#define M_DIM 256
#define P_DIM 32896            // 256*257/2
#define RTP_B 43008            // elements per batch: row-tile-padded + 8/row skew
#define CRTP_BYTES (176160768) // 2048*43008*2
#define WB_BYTES   (67371008)  // 32896*1024*2
#define XP_BYTES   (4194304)   // 2048*1024*2

typedef __attribute__((ext_vector_type(8))) short short8;
typedef __attribute__((ext_vector_type(4))) float f32x4;

#define GLD16(gsrc, ldst) __builtin_amdgcn_global_load_lds(                    \
    (const __attribute__((address_space(1))) unsigned int*)(gsrc),             \
    (__attribute__((address_space(3))) unsigned int*)(ldst), 16, 0, 0)

__device__ __forceinline__ unsigned short f2bf(float f) {
    unsigned int u = __float_as_uint(f);
    u += 0x7FFFu + ((u >> 16) & 1u);          // RNE to bf16
    return (unsigned short)(u >> 16);
}
__device__ __forceinline__ float bf2f(unsigned short h) {
    return __uint_as_float(((unsigned int)h) << 16);
}
// base offset of row r in the skewed row-tile-padded layout
__device__ __forceinline__ int rtp_base(int r) {
    const int g = r >> 6;                      // row-tile 0..3
    return (g + 1) * 64 * ((g << 5) + (r & 63)) + (r << 3);
}

// ---------------- prep: zero Crtp (pads must be 0 for maskless syrk) ----------------
__global__ void zero_kernel(uint4* __restrict__ p, long n16) {
    long i = (long)blockIdx.x * blockDim.x + threadIdx.x;
    const long stride = (long)gridDim.x * blockDim.x;
    const uint4 z = make_uint4(0u, 0u, 0u, 0u);
    for (; i < n16; i += stride) p[i] = z;
}

// ---------------- prep: X fp32 -> bf16 hi/lo planes ----------------
__global__ void prep_x(const float* __restrict__ X,
                       unsigned short* __restrict__ Xhi, unsigned short* __restrict__ Xlo) {
    const int i = blockIdx.x * blockDim.x + threadIdx.x;       // one float4
    float4 v = reinterpret_cast<const float4*>(X)[i];
    float f[4] = {v.x, v.y, v.z, v.w};
    ushort4 h, l;
    unsigned short hh[4], ll[4];
#pragma unroll
    for (int e = 0; e < 4; ++e) {
        hh[e] = f2bf(f[e]);
        ll[e] = f2bf(f[e] - bf2f(hh[e]));      // exact residual split
    }
    h.x = hh[0]; h.y = hh[1]; h.z = hh[2]; h.w = hh[3];
    l.x = ll[0]; l.y = ll[1]; l.z = ll[2]; l.w = ll[3];
    reinterpret_cast<ushort4*>(Xhi)[i] = h;
    reinterpret_cast<ushort4*>(Xlo)[i] = l;
}

// ---------------- prep: W fp32 -> bf16 ----------------
__global__ void prep_w(const float* __restrict__ W, unsigned short* __restrict__ Wb) {
    const int i = blockIdx.x * blockDim.x + threadIdx.x;
    float4 v = reinterpret_cast<const float4*>(W)[i];
    ushort4 h;
    h.x = f2bf(v.x); h.y = f2bf(v.y); h.z = f2bf(v.z); h.w = f2bf(v.w);
    reinterpret_cast<ushort4*>(Wb)[i] = h;
}

// ---------------- Stage 1: C = (Xhi+Xlo) @ Wb^T + bias, diag-ReLU, store rtp bf16 ------
// 128x128 tile, BK=64, 4 waves (2x2), wave tile 64x64 = 4x4 frags of 16x16x32 MFMA.
__global__ __launch_bounds__(256) void gemm1_kernel(
    const unsigned short* __restrict__ Xhi, const unsigned short* __restrict__ Xlo,
    const unsigned short* __restrict__ Wb, const float* __restrict__ bias,
    unsigned short* __restrict__ Crtp)
{
    __shared__ unsigned short lds[3 * 128 * 64];   // Ahi | Alo | B, 48 KiB
    unsigned short* const Ahi = lds;
    unsigned short* const Alo = lds + 128 * 64;
    unsigned short* const Bt  = lds + 2 * 128 * 64;

    const int tid  = threadIdx.x;
    const int lane = tid & 63;
    const int wid  = tid >> 6;
    const int wr = wid >> 1, wc = wid & 1;
    const int row0 = blockIdx.y << 7;
    const int col0 = blockIdx.x << 7;

    // staging: each wave stages rows [wid*32, wid*32+32) of each plane.
    // lane -> row offset lane>>3, chunk lane&7; source chunk pre-XOR'd by (row&7)=(lane>>3)
    const int srow8  = lane >> 3;
    const int schunk = (lane & 7) ^ srow8;
    const int wrow   = (wid << 5) + srow8;
    const unsigned short* gAh = Xhi + (size_t)(row0 + wrow) * IN_DIM + (schunk << 3);
    const unsigned short* gAl = Xlo + (size_t)(row0 + wrow) * IN_DIM + (schunk << 3);
    const unsigned short* gBw = Wb  + (size_t)(col0 + wrow) * IN_DIM + (schunk << 3);
    unsigned short* const lAh = Ahi + (wid << 5) * 64;
    unsigned short* const lAl = Alo + (wid << 5) * 64;
    unsigned short* const lBw = Bt  + (wid << 5) * 64;

    const int lr16 = lane & 15;
    const int kc   = lane >> 4;

    f32x4 acc[4][4];
#pragma unroll
    for (int m = 0; m < 4; ++m)
#pragma unroll
        for (int n = 0; n < 4; ++n) acc[m][n] = (f32x4){0.f, 0.f, 0.f, 0.f};

    for (int kt = 0; kt < 16; ++kt) {
        const int ko = kt << 6;
        __syncthreads();                       // prev compute done before overwrite
#pragma unroll
        for (int i = 0; i < 4; ++i) {
            GLD16(gAh + (size_t)(i * 8) * IN_DIM + ko, lAh + i * 8 * 64);
            GLD16(gAl + (size_t)(i * 8) * IN_DIM + ko, lAl + i * 8 * 64);
            GLD16(gBw + (size_t)(i * 8) * IN_DIM + ko, lBw + i * 8 * 64);
        }
        __syncthreads();                       // vmcnt(0) drain + barrier
#pragma unroll
        for (int s = 0; s < 2; ++s) {
            short8 ah[4], al[4], bv[4];
#pragma unroll
            for (int m = 0; m < 4; ++m) {
                const int r  = (wr << 6) + (m << 4) + lr16;
                const int ch = ((s << 2) + kc) ^ (r & 7);
                ah[m] = *reinterpret_cast<const short8*>(&Ahi[r * 64 + ch * 8]);
                al[m] = *reinterpret_cast<const short8*>(&Alo[r * 64 + ch * 8]);
            }
#pragma unroll
            for (int n = 0; n < 4; ++n) {
                const int r  = (wc << 6) + (n << 4) + lr16;
                const int ch = ((s << 2) + kc) ^ (r & 7);
                bv[n] = *reinterpret_cast<const short8*>(&Bt[r * 64 + ch * 8]);
            }
#pragma unroll
            for (int m = 0; m < 4; ++m)
#pragma unroll
                for (int n = 0; n < 4; ++n) {
                    acc[m][n] = __builtin_amdgcn_mfma_f32_16x16x32_bf16(ah[m], bv[n], acc[m][n], 0, 0, 0);
                    acc[m][n] = __builtin_amdgcn_mfma_f32_16x16x32_bf16(al[m], bv[n], acc[m][n], 0, 0, 0);
                }
        }
    }

    // epilogue: D col = lane&15, row = (lane>>4)*4 + reg (m91-verified)
#pragma unroll
    for (int n = 0; n < 4; ++n) {
        const int p = col0 + (wc << 6) + (n << 4) + lr16;     // packed tril index
        const float t = sqrtf((float)(8 * p + 1));
        const int rt = (int)((t - 1.0f) * 0.5f + 0.001f);     // tril row (exact, see margin)
        const int ct = p - ((rt * (rt + 1)) >> 1);            // tril col
        const int off = rtp_base(rt) + ct;
        const bool diag = (ct == rt);
        const float bvs = bias[p];
#pragma unroll
        for (int m = 0; m < 4; ++m) {
#pragma unroll
            for (int q = 0; q < 4; ++q) {
                const int brow = row0 + (wr << 6) + (m << 4) + (kc << 2) + q;
                float v = acc[m][n][q] + bvs;
                if (diag) v = fmaxf(v, 0.f);
                Crtp[(size_t)brow * RTP_B + off] = f2bf(v);
            }
        }
    }
}

// ---------------- Stage 2: O[b] = L_b @ L_b^T, maskless MFMA from padded LDS ----------
// One block per batch. LDS holds whole skewed-rtp L (86016 B). 16 tiles, k <= min(ti,tj),
// units balanced 8/8/7/7 over 4 waves. Pads are zero => no triangular masking needed.
__global__ __launch_bounds__(256) void syrk_kernel(
    const unsigned short* __restrict__ Crtp, float* __restrict__ O)
{
    __shared__ unsigned short Lt[RTP_B];       // 86016 B
    const int tid  = threadIdx.x;
    const int lane = tid & 63;
    const int wid  = tid >> 6;
    const int b    = blockIdx.x;
    const unsigned short* Cb = Crtp + (size_t)b * RTP_B;

    // linear stage: 84 x 1KiB global_load_lds (exact, no tail)
#pragma unroll
    for (int i = 0; i < 21; ++i) {
        const int g = wid * 21 + i;
        GLD16(Cb + g * 512 + (lane << 3), &Lt[g * 512]);
    }
    __syncthreads();

    const int lr16 = lane & 15;
    const int kc   = lane >> 4;
    float* Ob = O + (size_t)b * (M_DIM * M_DIM);

    const unsigned char LIST[4][5] = {
        {0x33, 0x22, 0x00, 0x00, 0x00},
        {0x23, 0x32, 0x01, 0x10, 0x00},
        {0x13, 0x31, 0x11, 0x03, 0x00},
        {0x12, 0x21, 0x30, 0x02, 0x20}};
    const int CNT[4] = {3, 4, 4, 5};
    const int cnt = CNT[wid];

    for (int tt = 0; tt < cnt; ++tt) {
        const int code = LIST[wid][tt];
        const int ti = code >> 4, tj = code & 15;

        int baseA[4], baseB[4];
#pragma unroll
        for (int m = 0; m < 4; ++m) {
            const int ia = (ti << 6) + (m << 4) + lr16;
            const int jb = (tj << 6) + (m << 4) + lr16;
            baseA[m] = rtp_base(ia) + (kc << 3);
            baseB[m] = rtp_base(jb) + (kc << 3);
        }
        f32x4 acc[4][4];
#pragma unroll
        for (int m = 0; m < 4; ++m)
#pragma unroll
            for (int n = 0; n < 4; ++n) acc[m][n] = (f32x4){0.f, 0.f, 0.f, 0.f};

        const int kmax = ti < tj ? ti : tj;
        for (int kt = 0; kt <= kmax; ++kt) {
#pragma unroll
            for (int s = 0; s < 2; ++s) {
                const int ko = (kt << 6) + (s << 5);
                short8 a[4], bb[4];
#pragma unroll
                for (int m = 0; m < 4; ++m)
                    a[m] = *reinterpret_cast<const short8*>(&Lt[baseA[m] + ko]);
#pragma unroll
                for (int n = 0; n < 4; ++n)
                    bb[n] = *reinterpret_cast<const short8*>(&Lt[baseB[n] + ko]);
#pragma unroll
                for (int m = 0; m < 4; ++m)
#pragma unroll
                    for (int n = 0; n < 4; ++n)
                        acc[m][n] = __builtin_amdgcn_mfma_f32_16x16x32_bf16(a[m], bb[n], acc[m][n], 0, 0, 0);
            }
        }
#pragma unroll
        for (int m = 0; m < 4; ++m) {
            const int i0 = (ti << 6) + (m << 4) + (kc << 2);
#pragma unroll
            for (int n = 0; n < 4; ++n) {
                const int j = (tj << 6) + (n << 4) + lr16;
#pragma unroll
                for (int q = 0; q < 4; ++q)
                    Ob[(size_t)(i0 + q) * M_DIM + j] = acc[m][n][q];
            }
        }
    }
}

extern "C" void kernel_launch(void* const* d_in, const int* in_sizes, int n_in,
                              void* d_out, int out_size, void* d_ws, size_t ws_size,
                              hipStream_t stream)
{
    (void)in_sizes; (void)n_in; (void)out_size; (void)ws_size;
    const float* x    = (const float*)d_in[0];
    const float* W    = (const float*)d_in[1];
    const float* bias = (const float*)d_in[2];
    float* O = (float*)d_out;

    // ws layout (251,920,384 B total; round-1 already used 269.5 MB safely):
    char* ws = (char*)d_ws;
    unsigned short* Crtp = (unsigned short*)ws;
    unsigned short* Wb   = (unsigned short*)(ws + CRTP_BYTES);
    unsigned short* Xhi  = (unsigned short*)(ws + CRTP_BYTES + WB_BYTES);
    unsigned short* Xlo  = (unsigned short*)(ws + CRTP_BYTES + WB_BYTES + XP_BYTES);

    zero_kernel<<<2048, 256, 0, stream>>>((uint4*)Crtp, CRTP_BYTES / 16);
    prep_x<<<(B_DIM * IN_DIM / 4) / 256, 256, 0, stream>>>(x, Xhi, Xlo);
    prep_w<<<(P_DIM * IN_DIM / 4) / 256, 256, 0, stream>>>(W, Wb);
    dim3 g1(P_DIM / 128, B_DIM / 128);   // (257, 16)
    gemm1_kernel<<<g1, dim3(256), 0, stream>>>(Xhi, Xlo, Wb, bias, Crtp);
    syrk_kernel<<<dim3(B_DIM), dim3(256), 0, stream>>>(Crtp, O);
}

// Round 3
// 446.595 us; speedup vs baseline: 5.2981x; 1.2521x over previous
//
#include <hip/hip_runtime.h>

#define B_DIM 2048
#define IN_DIM 1024
#define M_DIM 256
#define P_DIM 32896            // 256*257/2
#define RTP_B 43008            // elements per batch: row-tile-padded + 8/row skew
#define CRTP_BYTES (176160768) // 2048*43008*2
#define WB_BYTES   (67371008)  // 32896*1024*2

typedef __attribute__((ext_vector_type(8))) short short8;
typedef __attribute__((ext_vector_type(4))) float f32x4;

#define GLD16(gsrc, ldst) __builtin_amdgcn_global_load_lds(                    \
    (const __attribute__((address_space(1))) unsigned int*)(gsrc),             \
    (__attribute__((address_space(3))) unsigned int*)(ldst), 16, 0, 0)

__device__ __forceinline__ unsigned short f2bf(float f) {
    unsigned int u = __float_as_uint(f);
    u += 0x7FFFu + ((u >> 16) & 1u);          // RNE to bf16
    return (unsigned short)(u >> 16);
}
// base offset of row r in the skewed row-tile-padded layout
__device__ __forceinline__ int rtp_base(int r) {
    const int g = r >> 6;                      // row-tile 0..3
    return (g + 1) * 64 * ((g << 5) + (r & 63)) + (r << 3);
}

// ---------------- prep: zero ONLY the rtp pads (41 MB instead of 176 MB) ------------
// Row r's pad = [rtp_base(r)+r+1, rtp_base(r)+span), span = (r>>6)*64+72, len = 71-(r&63)
__global__ void pad_zero(unsigned short* __restrict__ Crtp) {
    const int r = threadIdx.x;                 // 256 rows
    const int b = blockIdx.x;                  // 2048 batches
    unsigned short* p = Crtp + (size_t)b * RTP_B + rtp_base(r) + r + 1;
    int n = 71 - (r & 63);
    if (((uintptr_t)p) & 2) { *p++ = 0; --n; } // align to 4B
    unsigned int* q = (unsigned int*)p;
    for (int i = 0; i < (n >> 1); ++i) q[i] = 0;
    if (n & 1) ((unsigned short*)q)[n - 1] = 0;
}

// ---------------- prep: X fp32 -> bf16 ----------------
__global__ void prep_x(const float* __restrict__ X, unsigned short* __restrict__ Xhi) {
    const int i = blockIdx.x * blockDim.x + threadIdx.x;       // one float4
    float4 v = reinterpret_cast<const float4*>(X)[i];
    ushort4 h;
    h.x = f2bf(v.x); h.y = f2bf(v.y); h.z = f2bf(v.z); h.w = f2bf(v.w);
    reinterpret_cast<ushort4*>(Xhi)[i] = h;
}

// ---------------- prep: W fp32 -> bf16 ----------------
__global__ void prep_w(const float* __restrict__ W, unsigned short* __restrict__ Wb) {
    const int i = blockIdx.x * blockDim.x + threadIdx.x;
    float4 v = reinterpret_cast<const float4*>(W)[i];
    ushort4 h;
    h.x = f2bf(v.x); h.y = f2bf(v.y); h.z = f2bf(v.z); h.w = f2bf(v.w);
    reinterpret_cast<ushort4*>(Wb)[i] = h;
}

// ---------------- Stage 1: C = Xhi @ Wb^T + bias, diag-ReLU, store rtp bf16 ----------
// 128x128 tile, BK=64, 4 waves (2x2), wave tile 64x64 = 4x4 frags of 16x16x32 MFMA.
// Grid: 4112 blocks, XCD-chunked swizzle (4112 = 8*514); work id w -> (rowtile w&15,
// coltile w>>4) so 16 consecutive work ids share one W panel; Xhi (4 MB) L2-resident.
__global__ __launch_bounds__(256) void gemm1_kernel(
    const unsigned short* __restrict__ Xhi,
    const unsigned short* __restrict__ Wb, const float* __restrict__ bias,
    unsigned short* __restrict__ Crtp)
{
    __shared__ unsigned short lds[2 * 128 * 64];   // A | B, 32 KiB
    unsigned short* const Ah = lds;
    unsigned short* const Bt = lds + 128 * 64;

    const int lin = blockIdx.y * 16 + blockIdx.x;  // dispatch-linear id
    const int w   = (lin & 7) * 514 + (lin >> 3);  // XCD-chunked (bijective: 4112=8*514)
    const int row0 = (w & 15) << 7;
    const int col0 = (w >> 4) << 7;

    const int tid  = threadIdx.x;
    const int lane = tid & 63;
    const int wid  = tid >> 6;
    const int wr = wid >> 1, wc = wid & 1;

    // staging: each wave stages rows [wid*32, wid*32+32) of each plane.
    // lane -> row offset lane>>3, chunk lane&7; source chunk pre-XOR'd by (row&7)
    const int srow8  = lane >> 3;
    const int schunk = (lane & 7) ^ srow8;
    const int wrow   = (wid << 5) + srow8;
    const unsigned short* gAh = Xhi + (size_t)(row0 + wrow) * IN_DIM + (schunk << 3);
    const unsigned short* gBw = Wb  + (size_t)(col0 + wrow) * IN_DIM + (schunk << 3);
    unsigned short* const lAh = Ah + (wid << 5) * 64;
    unsigned short* const lBw = Bt + (wid << 5) * 64;

    const int lr16 = lane & 15;
    const int kc   = lane >> 4;

    f32x4 acc[4][4];
#pragma unroll
    for (int m = 0; m < 4; ++m)
#pragma unroll
        for (int n = 0; n < 4; ++n) acc[m][n] = (f32x4){0.f, 0.f, 0.f, 0.f};

    for (int kt = 0; kt < 16; ++kt) {
        const int ko = kt << 6;
        __syncthreads();                       // prev compute done before overwrite
#pragma unroll
        for (int i = 0; i < 4; ++i) {
            GLD16(gAh + (size_t)(i * 8) * IN_DIM + ko, lAh + i * 8 * 64);
            GLD16(gBw + (size_t)(i * 8) * IN_DIM + ko, lBw + i * 8 * 64);
        }
        __syncthreads();                       // vmcnt(0) drain + barrier
#pragma unroll
        for (int s = 0; s < 2; ++s) {
            short8 av[4], bv[4];
#pragma unroll
            for (int m = 0; m < 4; ++m) {
                const int r  = (wr << 6) + (m << 4) + lr16;
                const int ch = ((s << 2) + kc) ^ (r & 7);
                av[m] = *reinterpret_cast<const short8*>(&Ah[r * 64 + ch * 8]);
            }
#pragma unroll
            for (int n = 0; n < 4; ++n) {
                const int r  = (wc << 6) + (n << 4) + lr16;
                const int ch = ((s << 2) + kc) ^ (r & 7);
                bv[n] = *reinterpret_cast<const short8*>(&Bt[r * 64 + ch * 8]);
            }
#pragma unroll
            for (int m = 0; m < 4; ++m)
#pragma unroll
                for (int n = 0; n < 4; ++n)
                    acc[m][n] = __builtin_amdgcn_mfma_f32_16x16x32_bf16(av[m], bv[n], acc[m][n], 0, 0, 0);
        }
    }

    // epilogue: D col = lane&15, row = (lane>>4)*4 + reg (m91-verified)
#pragma unroll
    for (int n = 0; n < 4; ++n) {
        const int p = col0 + (wc << 6) + (n << 4) + lr16;     // packed tril index
        const float t = sqrtf((float)(8 * p + 1));
        const int rt = (int)((t - 1.0f) * 0.5f + 0.001f);     // tril row
        const int ct = p - ((rt * (rt + 1)) >> 1);            // tril col
        const int off = rtp_base(rt) + ct;
        const bool diag = (ct == rt);
        const float bvs = bias[p];
#pragma unroll
        for (int m = 0; m < 4; ++m) {
#pragma unroll
            for (int q = 0; q < 4; ++q) {
                const int brow = row0 + (wr << 6) + (m << 4) + (kc << 2) + q;
                float v = acc[m][n][q] + bvs;
                if (diag) v = fmaxf(v, 0.f);
                Crtp[(size_t)brow * RTP_B + off] = f2bf(v);
            }
        }
    }
}

// ---------------- Stage 2: O[b] = L_b @ L_b^T, maskless MFMA from padded LDS ----------
// One block per batch. LDS holds whole skewed-rtp L (86016 B). 16 tiles, k <= min(ti,tj),
// units balanced 8/8/7/7 over 4 waves. Pads are zero => no triangular masking needed.
__global__ __launch_bounds__(256) void syrk_kernel(
    const unsigned short* __restrict__ Crtp, float* __restrict__ O)
{
    __shared__ unsigned short Lt[RTP_B];       // 86016 B
    const int tid  = threadIdx.x;
    const int lane = tid & 63;
    const int wid  = tid >> 6;
    const int b    = blockIdx.x;
    const unsigned short* Cb = Crtp + (size_t)b * RTP_B;

    // linear stage: 84 x 1KiB global_load_lds (exact, no tail)
#pragma unroll
    for (int i = 0; i < 21; ++i) {
        const int g = wid * 21 + i;
        GLD16(Cb + g * 512 + (lane << 3), &Lt[g * 512]);
    }
    __syncthreads();

    const int lr16 = lane & 15;
    const int kc   = lane >> 4;
    float* Ob = O + (size_t)b * (M_DIM * M_DIM);

    const unsigned char LIST[4][5] = {
        {0x33, 0x22, 0x00, 0x00, 0x00},
        {0x23, 0x32, 0x01, 0x10, 0x00},
        {0x13, 0x31, 0x11, 0x03, 0x00},
        {0x12, 0x21, 0x30, 0x02, 0x20}};
    const int CNT[4] = {3, 4, 4, 5};
    const int cnt = CNT[wid];

    for (int tt = 0; tt < cnt; ++tt) {
        const int code = LIST[wid][tt];
        const int ti = code >> 4, tj = code & 15;

        int baseA[4], baseB[4];
#pragma unroll
        for (int m = 0; m < 4; ++m) {
            const int ia = (ti << 6) + (m << 4) + lr16;
            const int jb = (tj << 6) + (m << 4) + lr16;
            baseA[m] = rtp_base(ia) + (kc << 3);
            baseB[m] = rtp_base(jb) + (kc << 3);
        }
        f32x4 acc[4][4];
#pragma unroll
        for (int m = 0; m < 4; ++m)
#pragma unroll
            for (int n = 0; n < 4; ++n) acc[m][n] = (f32x4){0.f, 0.f, 0.f, 0.f};

        const int kmax = ti < tj ? ti : tj;
        for (int kt = 0; kt <= kmax; ++kt) {
#pragma unroll
            for (int s = 0; s < 2; ++s) {
                const int ko = (kt << 6) + (s << 5);
                short8 a[4], bb[4];
#pragma unroll
                for (int m = 0; m < 4; ++m)
                    a[m] = *reinterpret_cast<const short8*>(&Lt[baseA[m] + ko]);
#pragma unroll
                for (int n = 0; n < 4; ++n)
                    bb[n] = *reinterpret_cast<const short8*>(&Lt[baseB[n] + ko]);
#pragma unroll
                for (int m = 0; m < 4; ++m)
#pragma unroll
                    for (int n = 0; n < 4; ++n)
                        acc[m][n] = __builtin_amdgcn_mfma_f32_16x16x32_bf16(a[m], bb[n], acc[m][n], 0, 0, 0);
            }
        }
#pragma unroll
        for (int m = 0; m < 4; ++m) {
            const int i0 = (ti << 6) + (m << 4) + (kc << 2);
#pragma unroll
            for (int n = 0; n < 4; ++n) {
                const int j = (tj << 6) + (n << 4) + lr16;
#pragma unroll
                for (int q = 0; q < 4; ++q)
                    Ob[(size_t)(i0 + q) * M_DIM + j] = acc[m][n][q];
            }
        }
    }
}

extern "C" void kernel_launch(void* const* d_in, const int* in_sizes, int n_in,
                              void* d_out, int out_size, void* d_ws, size_t ws_size,
                              hipStream_t stream)
{
    (void)in_sizes; (void)n_in; (void)out_size; (void)ws_size;
    const float* x    = (const float*)d_in[0];
    const float* W    = (const float*)d_in[1];
    const float* bias = (const float*)d_in[2];
    float* O = (float*)d_out;

    char* ws = (char*)d_ws;
    unsigned short* Crtp = (unsigned short*)ws;
    unsigned short* Wb   = (unsigned short*)(ws + CRTP_BYTES);
    unsigned short* Xhi  = (unsigned short*)(ws + CRTP_BYTES + WB_BYTES);

    pad_zero<<<B_DIM, 256, 0, stream>>>(Crtp);
    prep_x<<<(B_DIM * IN_DIM / 4) / 256, 256, 0, stream>>>(x, Xhi);
    prep_w<<<(P_DIM * IN_DIM / 4) / 256, 256, 0, stream>>>(W, Wb);
    gemm1_kernel<<<dim3(16, 257), dim3(256), 0, stream>>>(Xhi, Wb, bias, Crtp);
    syrk_kernel<<<dim3(B_DIM), dim3(256), 0, stream>>>(Crtp, O);
}

// Round 4
// 443.078 us; speedup vs baseline: 5.3401x; 1.0079x over previous
//
#include <hip/hip_runtime.h>

#define B_DIM 2048
#define IN_DIM 1024
#define M_DIM 256
#define P_DIM 32896            // 256*257/2
#define RTP_B 43008            // elements per batch: row-tile-padded + 8/row skew
#define CRTP_BYTES (176160768) // 2048*43008*2
#define WB_BYTES   (67371008)  // 32896*1024*2

typedef __attribute__((ext_vector_type(8))) short short8;
typedef __attribute__((ext_vector_type(4))) float f32x4;

#define GLD16(gsrc, ldst) __builtin_amdgcn_global_load_lds(                    \
    (const __attribute__((address_space(1))) unsigned int*)(gsrc),             \
    (__attribute__((address_space(3))) unsigned int*)(ldst), 16, 0, 0)

__device__ __forceinline__ unsigned short f2bf(float f) {
    unsigned int u = __float_as_uint(f);
    u += 0x7FFFu + ((u >> 16) & 1u);          // RNE to bf16
    return (unsigned short)(u >> 16);
}
// base offset of row r in the skewed row-tile-padded layout
__device__ __forceinline__ int rtp_base(int r) {
    const int g = r >> 6;                      // row-tile 0..3
    return (g + 1) * 64 * ((g << 5) + (r & 63)) + (r << 3);
}

// ---------------- prep: zero ONLY the rtp pads ----------------
__global__ void pad_zero(unsigned short* __restrict__ Crtp) {
    const int r = threadIdx.x;                 // 256 rows
    const int b = blockIdx.x;                  // 2048 batches
    unsigned short* p = Crtp + (size_t)b * RTP_B + rtp_base(r) + r + 1;
    int n = 71 - (r & 63);
    if (((uintptr_t)p) & 2) { *p++ = 0; --n; } // align to 4B
    unsigned int* q = (unsigned int*)p;
    for (int i = 0; i < (n >> 1); ++i) q[i] = 0;
    if (n & 1) ((unsigned short*)q)[n - 1] = 0;
}

// ---------------- prep: X fp32 -> bf16 ----------------
__global__ void prep_x(const float* __restrict__ X, unsigned short* __restrict__ Xhi) {
    const int i = blockIdx.x * blockDim.x + threadIdx.x;       // one float4
    float4 v = reinterpret_cast<const float4*>(X)[i];
    ushort4 h;
    h.x = f2bf(v.x); h.y = f2bf(v.y); h.z = f2bf(v.z); h.w = f2bf(v.w);
    reinterpret_cast<ushort4*>(Xhi)[i] = h;
}

// ---------------- prep: W fp32 -> bf16 ----------------
__global__ void prep_w(const float* __restrict__ W, unsigned short* __restrict__ Wb) {
    const int i = blockIdx.x * blockDim.x + threadIdx.x;
    float4 v = reinterpret_cast<const float4*>(W)[i];
    ushort4 h;
    h.x = f2bf(v.x); h.y = f2bf(v.y); h.z = f2bf(v.z); h.w = f2bf(v.w);
    reinterpret_cast<ushort4*>(Wb)[i] = h;
}

// ---------------- Stage 1: C = Xhi @ Wb^T + bias, diag-ReLU, store rtp bf16 ----------
// BM=256, BN=128, BK=64. 512 threads = 8 waves (4M x 2N), wave tile 64x64.
// Triple-buffered LDS (3 x 48KB), prefetch depth 2, counted vmcnt(6) at iter entry
// (never drains to 0 in steady state), 1 barrier/iter, setprio around MFMA clusters.
__global__ __launch_bounds__(512) void gemm1_kernel(
    const unsigned short* __restrict__ Xhi,
    const unsigned short* __restrict__ Wb, const float* __restrict__ bias,
    unsigned short* __restrict__ Crtp)
{
    __shared__ unsigned short lds[3 * 24576];      // per buf: A 16384 el | B 8192 el

    const int lin = blockIdx.x;
    const int w   = (lin & 7) * 257 + (lin >> 3);  // XCD-chunked bijective (2056 = 8*257)
    const int row0 = (w & 7) << 8;                 // 8 row tiles of 256
    const int col0 = (w >> 3) << 7;                // 257 col tiles of 128

    const int tid  = threadIdx.x;
    const int lane = tid & 63;
    const int wid  = tid >> 6;                     // 0..7
    const int wr   = wid >> 1;                     // 0..3
    const int wc   = wid & 1;                      // 0..1
    const int lr16 = lane & 15;
    const int kc   = lane >> 4;

    // staging: 48 x 1KB chunks per K-tile (A = chunks 0..31, B = 32..47);
    // wave stages chunks [6*wid, 6*wid+6). lane -> row lane>>3, 16B-chunk pre-XOR'd.
    const int srow = lane >> 3;
    const int sch  = (lane & 7) ^ srow;
    const unsigned short* gsrc[6];
    int loff[6];
#pragma unroll
    for (int i = 0; i < 6; ++i) {
        const int c = 6 * wid + i;
        if (c < 32) {
            gsrc[i] = Xhi + (size_t)(row0 + c * 8 + srow) * IN_DIM + (sch << 3);
            loff[i] = c * 512;
        } else {
            gsrc[i] = Wb + (size_t)(col0 + (c - 32) * 8 + srow) * IN_DIM + (sch << 3);
            loff[i] = 16384 + (c - 32) * 512;
        }
    }

#define STAGE(kt, bufo)                                                        \
    {                                                                          \
        _Pragma("unroll")                                                      \
        for (int i = 0; i < 6; ++i)                                            \
            GLD16(gsrc[i] + ((kt) << 6), &lds[(bufo) + loff[i]]);              \
    }

    f32x4 acc[4][4];
#pragma unroll
    for (int m = 0; m < 4; ++m)
#pragma unroll
        for (int n = 0; n < 4; ++n) acc[m][n] = (f32x4){0.f, 0.f, 0.f, 0.f};

    int o0 = 0, o1 = 24576, o2 = 49152;
    STAGE(0, o0);
    STAGE(1, o1);

    for (int it = 0; it < 16; ++it) {
        if (it < 15) asm volatile("s_waitcnt vmcnt(6)" ::: "memory");
        else         asm volatile("s_waitcnt vmcnt(0)" ::: "memory");
        __builtin_amdgcn_s_barrier();
        asm volatile("" ::: "memory");             // keep ds_reads below the barrier

        const int cb = o0;
        // ---- phase 0: k-half s=0 ----
        short8 av[4], bv[4];
#pragma unroll
        for (int m = 0; m < 4; ++m) {
            const int r = (wr << 6) + (m << 4) + lr16;
            av[m] = *reinterpret_cast<const short8*>(&lds[cb + r * 64 + (kc ^ (r & 7)) * 8]);
        }
#pragma unroll
        for (int n = 0; n < 4; ++n) {
            const int r = (wc << 6) + (n << 4) + lr16;
            bv[n] = *reinterpret_cast<const short8*>(&lds[cb + 16384 + r * 64 + (kc ^ (r & 7)) * 8]);
        }
        if (it < 14) STAGE(it + 2, o2);            // prefetch depth 2
        __builtin_amdgcn_s_setprio(1);
#pragma unroll
        for (int m = 0; m < 4; ++m)
#pragma unroll
            for (int n = 0; n < 4; ++n)
                acc[m][n] = __builtin_amdgcn_mfma_f32_16x16x32_bf16(av[m], bv[n], acc[m][n], 0, 0, 0);
        __builtin_amdgcn_s_setprio(0);

        // ---- phase 1: k-half s=1 ----
#pragma unroll
        for (int m = 0; m < 4; ++m) {
            const int r = (wr << 6) + (m << 4) + lr16;
            av[m] = *reinterpret_cast<const short8*>(&lds[cb + r * 64 + ((4 + kc) ^ (r & 7)) * 8]);
        }
#pragma unroll
        for (int n = 0; n < 4; ++n) {
            const int r = (wc << 6) + (n << 4) + lr16;
            bv[n] = *reinterpret_cast<const short8*>(&lds[cb + 16384 + r * 64 + ((4 + kc) ^ (r & 7)) * 8]);
        }
        __builtin_amdgcn_s_setprio(1);
#pragma unroll
        for (int m = 0; m < 4; ++m)
#pragma unroll
            for (int n = 0; n < 4; ++n)
                acc[m][n] = __builtin_amdgcn_mfma_f32_16x16x32_bf16(av[m], bv[n], acc[m][n], 0, 0, 0);
        __builtin_amdgcn_s_setprio(0);

        const int t = o0; o0 = o1; o1 = o2; o2 = t;   // rotate ring
    }
#undef STAGE

    // epilogue: D col = lane&15, row = (lane>>4)*4 + reg
#pragma unroll
    for (int n = 0; n < 4; ++n) {
        const int p = col0 + (wc << 6) + (n << 4) + lr16;     // packed tril index
        const float t = sqrtf((float)(8 * p + 1));
        const int rt = (int)((t - 1.0f) * 0.5f + 0.001f);     // tril row
        const int ct = p - ((rt * (rt + 1)) >> 1);            // tril col
        const int off = rtp_base(rt) + ct;
        const bool diag = (ct == rt);
        const float bvs = bias[p];
#pragma unroll
        for (int m = 0; m < 4; ++m) {
#pragma unroll
            for (int q = 0; q < 4; ++q) {
                const int brow = row0 + (wr << 6) + (m << 4) + (kc << 2) + q;
                float v = acc[m][n][q] + bvs;
                if (diag) v = fmaxf(v, 0.f);
                Crtp[(size_t)brow * RTP_B + off] = f2bf(v);
            }
        }
    }
}

// ---------------- Stage 2: O[b] = L_b @ L_b^T, maskless MFMA from padded LDS ----------
__global__ __launch_bounds__(256) void syrk_kernel(
    const unsigned short* __restrict__ Crtp, float* __restrict__ O)
{
    __shared__ unsigned short Lt[RTP_B];       // 86016 B
    const int tid  = threadIdx.x;
    const int lane = tid & 63;
    const int wid  = tid >> 6;
    const int b    = blockIdx.x;
    const unsigned short* Cb = Crtp + (size_t)b * RTP_B;

#pragma unroll
    for (int i = 0; i < 21; ++i) {
        const int g = wid * 21 + i;
        GLD16(Cb + g * 512 + (lane << 3), &Lt[g * 512]);
    }
    __syncthreads();

    const int lr16 = lane & 15;
    const int kc   = lane >> 4;
    float* Ob = O + (size_t)b * (M_DIM * M_DIM);

    const unsigned char LIST[4][5] = {
        {0x33, 0x22, 0x00, 0x00, 0x00},
        {0x23, 0x32, 0x01, 0x10, 0x00},
        {0x13, 0x31, 0x11, 0x03, 0x00},
        {0x12, 0x21, 0x30, 0x02, 0x20}};
    const int CNT[4] = {3, 4, 4, 5};
    const int cnt = CNT[wid];

    for (int tt = 0; tt < cnt; ++tt) {
        const int code = LIST[wid][tt];
        const int ti = code >> 4, tj = code & 15;

        int baseA[4], baseB[4];
#pragma unroll
        for (int m = 0; m < 4; ++m) {
            const int ia = (ti << 6) + (m << 4) + lr16;
            const int jb = (tj << 6) + (m << 4) + lr16;
            baseA[m] = rtp_base(ia) + (kc << 3);
            baseB[m] = rtp_base(jb) + (kc << 3);
        }
        f32x4 acc[4][4];
#pragma unroll
        for (int m = 0; m < 4; ++m)
#pragma unroll
            for (int n = 0; n < 4; ++n) acc[m][n] = (f32x4){0.f, 0.f, 0.f, 0.f};

        const int kmax = ti < tj ? ti : tj;
        for (int kt = 0; kt <= kmax; ++kt) {
#pragma unroll
            for (int s = 0; s < 2; ++s) {
                const int ko = (kt << 6) + (s << 5);
                short8 a[4], bb[4];
#pragma unroll
                for (int m = 0; m < 4; ++m)
                    a[m] = *reinterpret_cast<const short8*>(&Lt[baseA[m] + ko]);
#pragma unroll
                for (int n = 0; n < 4; ++n)
                    bb[n] = *reinterpret_cast<const short8*>(&Lt[baseB[n] + ko]);
#pragma unroll
                for (int m = 0; m < 4; ++m)
#pragma unroll
                    for (int n = 0; n < 4; ++n)
                        acc[m][n] = __builtin_amdgcn_mfma_f32_16x16x32_bf16(a[m], bb[n], acc[m][n], 0, 0, 0);
            }
        }
#pragma unroll
        for (int m = 0; m < 4; ++m) {
            const int i0 = (ti << 6) + (m << 4) + (kc << 2);
#pragma unroll
            for (int n = 0; n < 4; ++n) {
                const int j = (tj << 6) + (n << 4) + lr16;
#pragma unroll
                for (int q = 0; q < 4; ++q)
                    Ob[(size_t)(i0 + q) * M_DIM + j] = acc[m][n][q];
            }
        }
    }
}

extern "C" void kernel_launch(void* const* d_in, const int* in_sizes, int n_in,
                              void* d_out, int out_size, void* d_ws, size_t ws_size,
                              hipStream_t stream)
{
    (void)in_sizes; (void)n_in; (void)out_size; (void)ws_size;
    const float* x    = (const float*)d_in[0];
    const float* W    = (const float*)d_in[1];
    const float* bias = (const float*)d_in[2];
    float* O = (float*)d_out;

    char* ws = (char*)d_ws;
    unsigned short* Crtp = (unsigned short*)ws;
    unsigned short* Wb   = (unsigned short*)(ws + CRTP_BYTES);
    unsigned short* Xhi  = (unsigned short*)(ws + CRTP_BYTES + WB_BYTES);

    pad_zero<<<B_DIM, 256, 0, stream>>>(Crtp);
    prep_x<<<(B_DIM * IN_DIM / 4) / 256, 256, 0, stream>>>(x, Xhi);
    prep_w<<<(P_DIM * IN_DIM / 4) / 256, 256, 0, stream>>>(W, Wb);
    gemm1_kernel<<<dim3(2056), dim3(512), 0, stream>>>(Xhi, Wb, bias, Crtp);
    syrk_kernel<<<dim3(B_DIM), dim3(256), 0, stream>>>(Crtp, O);
}